// Round 1
// 320.351 us; speedup vs baseline: 1.0460x; 1.0460x over previous
//
#include <hip/hip_runtime.h>

// MergeAdapter: out = x + Up_n(relu(Down_n(x))), merged expert weights.
// N=16, S=2048, H=1024, Kexp=8, D=256. fp32 in/out, bf16 MFMA internally.
//
// Round 5: occupancy fix. Round 4 was latency-bound (MfmaUtil 9.7%, HBM 29%,
// Occupancy 20.7%): 128 KB LDS -> 1 block/CU, so every barrier's vmcnt(0)
// drain had no co-resident block to hide behind. This round halves the
// M-tile (64 rows/block, grid 512 = 2 blocks/CU) and fits LDS in exactly
// 80 KB/block (2 x 80 KB = 160 KB/CU):
//   phase 1: dbuf of [x 64x64 bf16 (8 KB) + Wd 256x64 bf16 (32 KB)] = 80 KB
//   phase 2: Rs 64x256 (32 KB) + Wu 64-col chunk (32 KB); R hoisted to
//            registers (af[2][8] = 64 VGPR) frees Rs for the chunk dbuf.
// __launch_bounds__(512,4) caps regs at 128 so 4 waves/SIMD fit.
//
// Swizzle scheme unchanged: 16-B slots within a row; physical_slot =
// logical_slot XOR (row & 7) on the low 3 bits. For global_load_lds staging
// (linear LDS dest) the global source column is permuted instead.

typedef unsigned short u16;
typedef __bf16 bf16x8 __attribute__((ext_vector_type(8)));
typedef float f32x4 __attribute__((ext_vector_type(4)));

__device__ __forceinline__ u16 f2bf(float f) {
    union { float f; unsigned int i; } v; v.f = f;
    unsigned int r = v.i + 0x7fffu + ((v.i >> 16) & 1u);  // RNE
    return (u16)(r >> 16);
}

__device__ __forceinline__ void gload_lds16(const u16* g, u16* l) {
    __builtin_amdgcn_global_load_lds(
        (const __attribute__((address_space(1))) void*)g,
        (__attribute__((address_space(3))) void*)l,
        16, 0, 0);
}

__device__ __forceinline__ void store8(u16* dst, float4 a, float4 b) {
    union { uint4 u; u16 s[8]; } cv;
    cv.s[0]=f2bf(a.x); cv.s[1]=f2bf(a.y); cv.s[2]=f2bf(a.z); cv.s[3]=f2bf(a.w);
    cv.s[4]=f2bf(b.x); cv.s[5]=f2bf(b.y); cv.s[6]=f2bf(b.z); cv.s[7]=f2bf(b.w);
    *(uint4*)dst = cv.u;
}

// ---------------------------------------------------------------------------
// Kernel 0: merge weights + biases (fp32 in -> bf16 weights / fp32 biases).
// ---------------------------------------------------------------------------
__global__ __launch_bounds__(256)
void merge_kernel(const float* __restrict__ prob,
                  const float* __restrict__ w_down, const float* __restrict__ b_down,
                  const float* __restrict__ w_up,   const float* __restrict__ b_up,
                  u16* __restrict__ Wd, u16* __restrict__ Wu,
                  float* __restrict__ bd, float* __restrict__ bu)
{
    __shared__ float sp[128];          // prob (16 x 8)
    const int tid = threadIdx.x;
    if (tid < 128) sp[tid] = prob[tid];
    __syncthreads();

    const int bid = blockIdx.x;
    const int E = 256 * 1024;

    if (bid < 256) {
        int v = bid * 256 + tid;       // 0..65535 vector slots (8 elems each)
        const bool down = (v < 32768);
        const int vv = down ? v : (v - 32768);
        const float* W = down ? w_down : w_up;
        u16* O = down ? Wd : Wu;
        const size_t e = (size_t)vv * 8;

        float wf[8][8];
        #pragma unroll
        for (int k = 0; k < 8; ++k) {
            const float4 f0 = *(const float4*)(W + (size_t)k * E + e);
            const float4 f1 = *(const float4*)(W + (size_t)k * E + e + 4);
            wf[k][0] = f0.x; wf[k][1] = f0.y; wf[k][2] = f0.z; wf[k][3] = f0.w;
            wf[k][4] = f1.x; wf[k][5] = f1.y; wf[k][6] = f1.z; wf[k][7] = f1.w;
        }
        for (int n = 0; n < 16; ++n) {
            float a[8] = {0.f,0.f,0.f,0.f,0.f,0.f,0.f,0.f};
            #pragma unroll
            for (int k = 0; k < 8; ++k) {
                const float p = sp[n * 8 + k];
                #pragma unroll
                for (int j = 0; j < 8; ++j) a[j] = fmaf(p, wf[k][j], a[j]);
            }
            union { uint4 u; u16 s[8]; } ov;
            #pragma unroll
            for (int j = 0; j < 8; ++j) ov.s[j] = f2bf(a[j]);
            *(uint4*)(O + (size_t)n * E + e) = ov.u;
        }
    } else {
        int idx = (bid - 256) * 256 + tid;   // 0..20479
        if (idx < 16 * 256) {
            const int n = idx >> 8, d = idx & 255;
            float s = 0.f;
            #pragma unroll
            for (int k = 0; k < 8; ++k)
                s = fmaf(sp[n * 8 + k], b_down[k * 256 + d], s);
            bd[idx] = s;
        } else {
            const int i2 = idx - 4096;
            const int n = i2 >> 10, h = i2 & 1023;
            float s = 0.f;
            #pragma unroll
            for (int k = 0; k < 8; ++k)
                s = fmaf(sp[n * 8 + k], b_up[k * 1024 + h], s);
            bu[i2] = s;
        }
    }
}

// ---------------------------------------------------------------------------
// Fused adapter kernel. Grid 512, 512 thr (8 waves), 64 rows/block,
// 80 KB LDS -> 2 blocks/CU.
// ---------------------------------------------------------------------------
__global__ __launch_bounds__(512, 4)
void fused_adapter(const float* __restrict__ x, const u16* __restrict__ Wd,
                   const u16* __restrict__ Wu, const float* __restrict__ bd,
                   const float* __restrict__ bu, float* __restrict__ out)
{
    __shared__ __align__(16) u16 lds[40960];   // 80 KB total

    const int tid  = threadIdx.x;
    const int lane = tid & 63;
    const int wave = tid >> 6;               // 0..7
    const int quad = lane >> 4, rl = lane & 15;
    const int rxl  = rl & 7;

    // swizzle: each batch's 32 M-blocks share one XCD -> Wd/Wu L2-hot
    const int id = blockIdx.x;               // 0..511
    const int batch = (id & 7) * 2 + ((id >> 3) & 1);
    const int mblk  = id >> 4;               // 0..31

    const float* xb  = x  + (size_t)batch * 2048 * 1024 + (size_t)mblk * 64 * 1024;
    const u16*   Wdb = Wd + (size_t)batch * 256 * 1024;
    const u16*   Wub = Wu + (size_t)batch * 1024 * 256;
    const float* bdb = bd + batch * 256;
    const float* bub = bu + batch * 1024;
    float*       ob  = out + (size_t)batch * 2048 * 1024 + (size_t)mblk * 64 * 1024;

    // ================= phase 1: R = relu(x @ Wd^T + bd), dbuf BK=64 ========
    const int wm1 = wave >> 2, wn1 = wave & 3;   // 2x4 over 64x256

    u16* const b0x = lds;          u16* const b0w = lds + 4096;   // even iters
    u16* const b1x = lds + 20480;  u16* const b1w = lds + 24576;  // odd iters

    // x staging geometry (1 store8/thread, 8-slot rows, 64-elem rows)
    const int xrow = tid >> 3, xsl = tid & 7;
    const int xdst = (xrow * 8 + (xsl ^ (xrow & 7))) * 8;  // swizzled LDS elems
    // Wd staging: 4 gloads/thread; permuted global col (row&7 const over r)
    const int wrow  = tid >> 3;                              // + r*64
    const int wgcol = ((tid & 7) ^ (wrow & 7)) * 8;

    f32x4 acc1[2][4] = {};

    // prologue: stage iter 0 into buf0
    {
        const float4 a0 = *(const float4*)(xb + (size_t)xrow * 1024 + xsl * 8);
        const float4 a1 = *(const float4*)(xb + (size_t)xrow * 1024 + xsl * 8 + 4);
        #pragma unroll
        for (int r = 0; r < 4; ++r)
            gload_lds16(Wdb + (size_t)(r * 64 + wrow) * 1024 + wgcol,
                        b0w + (size_t)(r * 512 + wave * 64) * 8);
        store8(b0x + xdst, a0, a1);
    }
    __syncthreads();

    for (int it = 0; it < 16; ++it) {
        u16* cx = (it & 1) ? b1x : b0x;
        u16* cw = (it & 1) ? b1w : b0w;
        u16* nx = (it & 1) ? b0x : b1x;
        u16* nw = (it & 1) ? b0w : b1w;
        const int k1 = (it + 1) * 64;

        float4 a0, a1;
        if (it < 15) {
            a0 = *(const float4*)(xb + (size_t)xrow * 1024 + k1 + xsl * 8);
            a1 = *(const float4*)(xb + (size_t)xrow * 1024 + k1 + xsl * 8 + 4);
            #pragma unroll
            for (int r = 0; r < 4; ++r)
                gload_lds16(Wdb + (size_t)(r * 64 + wrow) * 1024 + k1 + wgcol,
                            nw + (size_t)(r * 512 + wave * 64) * 8);
        }

        #pragma unroll
        for (int kk = 0; kk < 64; kk += 32) {
            bf16x8 av[2], bv[4];
            #pragma unroll
            for (int mi = 0; mi < 2; ++mi)
                av[mi] = *(const bf16x8*)(cx + (wm1 * 32 + mi * 16 + rl) * 64
                                          + ((kk / 8 + quad) ^ rxl) * 8);
            #pragma unroll
            for (int ni = 0; ni < 4; ++ni)
                bv[ni] = *(const bf16x8*)(cw + (wn1 * 64 + ni * 16 + rl) * 64
                                          + ((kk / 8 + quad) ^ rxl) * 8);
            #pragma unroll
            for (int mi = 0; mi < 2; ++mi)
                #pragma unroll
                for (int ni = 0; ni < 4; ++ni)
                    acc1[mi][ni] = __builtin_amdgcn_mfma_f32_16x16x32_bf16(
                        av[mi], bv[ni], acc1[mi][ni], 0, 0, 0);
        }

        if (it < 15) store8(nx + xdst, a0, a1);
        __syncthreads();
    }

    // epilogue 1: bias + relu -> Rs (lds[0..16384)), 32-slot rows, swizzled
    #pragma unroll
    for (int ni = 0; ni < 4; ++ni) {
        const int col = wn1 * 64 + ni * 16 + rl;
        const float bval = bdb[col];
        const int lbc = col >> 3, hi = lbc & 24, c7 = lbc & 7, cl = col & 7;
        #pragma unroll
        for (int mi = 0; mi < 2; ++mi)
            #pragma unroll
            for (int i = 0; i < 4; ++i) {
                const int row = wm1 * 32 + mi * 16 + quad * 4 + i;
                const int phys = hi | (c7 ^ (row & 7));
                lds[row * 256 + phys * 8 + cl] =
                    f2bf(fmaxf(acc1[mi][ni][i] + bval, 0.0f));
            }
    }
    __syncthreads();

    // ================= phase 2: out = x + R @ Wu^T + bu ====================
    const int wm2 = wave >> 2, wn2 = wave & 3;   // 32 rows x 16 cols per chunk

    // Wu chunk staging: 4 gloads/thread, 32-slot rows (256 elems), 64 rows
    const int srow = tid >> 5, ss = tid & 31;    // row = c*64 + rr*16 + srow
    const int wugcol = ((ss & 24) | ((ss & 7) ^ (srow & 7))) * 8;

    auto stage_wu = [&](int c, u16* buf) {
        #pragma unroll
        for (int rr = 0; rr < 4; ++rr)
            gload_lds16(Wub + (size_t)(c * 64 + rr * 16 + srow) * 256 + wugcol,
                        buf + (size_t)(rr * 512 + wave * 64) * 8);
    };

    stage_wu(0, lds + 16384);    // chunk 0 into [16384,32768) while af loads

    // hoist R A-fragments to registers: af[mi][t], 64 VGPRs
    bf16x8 af[2][8];
    #pragma unroll
    for (int mi = 0; mi < 2; ++mi) {
        const int rowb = (wm2 * 32 + mi * 16 + rl) * 256;
        #pragma unroll
        for (int t = 0; t < 8; ++t) {
            const int lb = t * 4 + quad;
            const int phys = (lb & 24) | ((lb & 7) ^ rxl);
            af[mi][t] = *(const bf16x8*)(lds + rowb + phys * 8);
        }
    }
    __syncthreads();   // af complete (Rs region free) + chunk 0 DMA drained

    u16* cur = lds + 16384;
    u16* nxt = lds;                // reuses the freed Rs region
    for (int c = 0; c < 16; ++c) {
        if (c < 15) stage_wu(c + 1, nxt);

        f32x4 acc2[2] = {};
        #pragma unroll
        for (int t = 0; t < 8; ++t) {
            const int lb = t * 4 + quad;
            const int phys = (lb & 24) | ((lb & 7) ^ rxl);
            const bf16x8 bv = *(const bf16x8*)(cur + (wn2 * 16 + rl) * 256
                                               + phys * 8);
            #pragma unroll
            for (int mi = 0; mi < 2; ++mi)
                acc2[mi] = __builtin_amdgcn_mfma_f32_16x16x32_bf16(
                    af[mi][t], bv, acc2[mi], 0, 0, 0);
        }

        // epilogue 2: bias + fp32 residual -> fp32 out
        const int colg = c * 64 + wn2 * 16 + rl;
        const float bval = bub[colg];
        #pragma unroll
        for (int mi = 0; mi < 2; ++mi)
            #pragma unroll
            for (int i = 0; i < 4; ++i) {
                const int rowl = wm2 * 32 + mi * 16 + quad * 4 + i;
                const size_t off = (size_t)rowl * 1024 + colg;
                ob[off] = acc2[mi][i] + bval + xb[off];
            }

        if (c < 15) {
            u16* t2 = cur; cur = nxt; nxt = t2;
            __syncthreads();   // drains chunk c+1 DMA; frees old cur for c+2
        }
    }
}

// ---------------------------------------------------------------------------
extern "C" void kernel_launch(void* const* d_in, const int* in_sizes, int n_in,
                              void* d_out, int out_size, void* d_ws, size_t ws_size,
                              hipStream_t stream) {
    const float* hidden = (const float*)d_in[0];   // (16, 2048, 1024) fp32
    const float* prob   = (const float*)d_in[1];   // (16, 8) fp32
    const float* w_down = (const float*)d_in[2];   // (8, 256, 1024) fp32
    const float* b_down = (const float*)d_in[3];   // (8, 256) fp32
    const float* w_up   = (const float*)d_in[4];   // (8, 1024, 256) fp32
    const float* b_up   = (const float*)d_in[5];   // (8, 1024) fp32
    float* out = (float*)d_out;                    // (16, 2048, 1024) fp32

    // workspace: merged weights (bf16) + biases (fp32), ~16.1 MB
    u16* Wd = (u16*)d_ws;                               // 16*256*1024 bf16
    u16* Wu = Wd + (size_t)16 * 256 * 1024;             // 16*1024*256 bf16
    float* bd = (float*)(Wu + (size_t)16 * 1024 * 256); // 16*256 f32
    float* bu = bd + 16 * 256;                          // 16*1024 f32

    merge_kernel<<<336, 256, 0, stream>>>(prob, w_down, b_down, w_up, b_up,
                                          Wd, Wu, bd, bu);

    fused_adapter<<<512, 512, 0, stream>>>(hidden, Wd, Wu, bd, bu, out);
}

// Round 4
// 300.276 us; speedup vs baseline: 1.1159x; 1.0669x over previous
//
#include <hip/hip_runtime.h>

// MergeAdapter: out = x + Up_n(relu(Down_n(x))), merged expert weights.
// N=16, S=2048, H=1024, Kexp=8, D=256. fp32 in/out, bf16 MFMA internally.
//
// Round 6 (3rd submit; two GPUAcquisitionTimeouts, kernel never ran).
// Counted-vmcnt deep pipeline (T3+T4). R5 was still latency-bound
// (HBM 29%, MfmaUtil 11%) because every __syncthreads drains vmcnt(0) --
// ~9000 cycles/segment. This round: grid 256 (1 block/CU), M-tile 128,
// 144 KB LDS:
//   phase 1: ring-3 buffers (x 128x64 bf16 8KB + Wd 256x64 bf16 32KB each),
//            DMA + x-reg loads issued 2 iters ahead; raw s_barrier with
//            s_waitcnt vmcnt(8) in steady state (never 0 in-loop).
//   phase 2: Rs 128x256 (64KB, overlays dead ring bufs), af in regs (64 VGPR),
//            Wu 64-col chunk dbuf (2x32KB) with counted waits; residual x +
//            bias for chunk c+1 prefetched to regs during chunk c.
// vmcnt math accounts for gfx9 semantics: stores count in vmcnt; waits are
// exact group counts, issue-group order pinned with asm memory fences.
//
// LDS map (u16 elems): ring buf k at k*24576 (x: +0 8192, Wd: +8192 16384).
// Phase 2: Rs at [0,32768) (bufs dead), wu0 at 32768 (=wbuf1), wu1 at 49152.

typedef unsigned short u16;
typedef __bf16 bf16x8 __attribute__((ext_vector_type(8)));
typedef float f32x4 __attribute__((ext_vector_type(4)));

__device__ __forceinline__ u16 f2bf(float f) {
    union { float f; unsigned int i; } v; v.f = f;
    unsigned int r = v.i + 0x7fffu + ((v.i >> 16) & 1u);  // RNE
    return (u16)(r >> 16);
}

__device__ __forceinline__ void gload_lds16(const u16* g, u16* l) {
    __builtin_amdgcn_global_load_lds(
        (const __attribute__((address_space(1))) void*)g,
        (__attribute__((address_space(3))) void*)l,
        16, 0, 0);
}

__device__ __forceinline__ void store8(u16* dst, float4 a, float4 b) {
    union { uint4 u; u16 s[8]; } cv;
    cv.s[0]=f2bf(a.x); cv.s[1]=f2bf(a.y); cv.s[2]=f2bf(a.z); cv.s[3]=f2bf(a.w);
    cv.s[4]=f2bf(b.x); cv.s[5]=f2bf(b.y); cv.s[6]=f2bf(b.z); cv.s[7]=f2bf(b.w);
    *(uint4*)dst = cv.u;
}

#define MEMF() asm volatile("" ::: "memory")

__device__ __forceinline__ void barx() {
    asm volatile("" ::: "memory");
    __builtin_amdgcn_s_barrier();
    asm volatile("" ::: "memory");
}

// ---------------------------------------------------------------------------
// Kernel 0: merge weights + biases (fp32 in -> bf16 weights / fp32 biases).
// ---------------------------------------------------------------------------
__global__ __launch_bounds__(256)
void merge_kernel(const float* __restrict__ prob,
                  const float* __restrict__ w_down, const float* __restrict__ b_down,
                  const float* __restrict__ w_up,   const float* __restrict__ b_up,
                  u16* __restrict__ Wd, u16* __restrict__ Wu,
                  float* __restrict__ bd, float* __restrict__ bu)
{
    __shared__ float sp[128];          // prob (16 x 8)
    const int tid = threadIdx.x;
    if (tid < 128) sp[tid] = prob[tid];
    __syncthreads();

    const int bid = blockIdx.x;
    const int E = 256 * 1024;

    if (bid < 256) {
        int v = bid * 256 + tid;       // 0..65535 vector slots (8 elems each)
        const bool down = (v < 32768);
        const int vv = down ? v : (v - 32768);
        const float* W = down ? w_down : w_up;
        u16* O = down ? Wd : Wu;
        const size_t e = (size_t)vv * 8;

        float wf[8][8];
        #pragma unroll
        for (int k = 0; k < 8; ++k) {
            const float4 f0 = *(const float4*)(W + (size_t)k * E + e);
            const float4 f1 = *(const float4*)(W + (size_t)k * E + e + 4);
            wf[k][0] = f0.x; wf[k][1] = f0.y; wf[k][2] = f0.z; wf[k][3] = f0.w;
            wf[k][4] = f1.x; wf[k][5] = f1.y; wf[k][6] = f1.z; wf[k][7] = f1.w;
        }
        for (int n = 0; n < 16; ++n) {
            float a[8] = {0.f,0.f,0.f,0.f,0.f,0.f,0.f,0.f};
            #pragma unroll
            for (int k = 0; k < 8; ++k) {
                const float p = sp[n * 8 + k];
                #pragma unroll
                for (int j = 0; j < 8; ++j) a[j] = fmaf(p, wf[k][j], a[j]);
            }
            union { uint4 u; u16 s[8]; } ov;
            #pragma unroll
            for (int j = 0; j < 8; ++j) ov.s[j] = f2bf(a[j]);
            *(uint4*)(O + (size_t)n * E + e) = ov.u;
        }
    } else {
        int idx = (bid - 256) * 256 + tid;   // 0..20479
        if (idx < 16 * 256) {
            const int n = idx >> 8, d = idx & 255;
            float s = 0.f;
            #pragma unroll
            for (int k = 0; k < 8; ++k)
                s = fmaf(sp[n * 8 + k], b_down[k * 256 + d], s);
            bd[idx] = s;
        } else {
            const int i2 = idx - 4096;
            const int n = i2 >> 10, h = i2 & 1023;
            float s = 0.f;
            #pragma unroll
            for (int k = 0; k < 8; ++k)
                s = fmaf(sp[n * 8 + k], b_up[k * 1024 + h], s);
            bu[i2] = s;
        }
    }
}

// ---------------------------------------------------------------------------
// Fused adapter kernel. Grid 256 (1 block/CU), 512 thr (8 waves), 144 KB LDS.
// ---------------------------------------------------------------------------
__global__ __launch_bounds__(512, 2)
void fused_adapter(const float* __restrict__ x, const u16* __restrict__ Wd,
                   const u16* __restrict__ Wu, const float* __restrict__ bd,
                   const float* __restrict__ bu, float* __restrict__ out)
{
    __shared__ __align__(16) u16 lds[73728];   // 144 KB

    const int tid  = threadIdx.x;
    const int lane = tid & 63;
    const int wave = tid >> 6;               // 0..7
    const int quad = lane >> 4, rl = lane & 15;
    const int rxl  = rl & 7;

    // XCD grouping: 2 batches per XCD -> Wd/Wu (1 MB/batch) L2-hot
    const int id = blockIdx.x;               // 0..255
    const int batch = (id & 7) * 2 + ((id >> 3) & 1);
    const int mblk  = id >> 4;               // 0..15

    const float* xb  = x  + (size_t)batch * 2048 * 1024 + (size_t)mblk * 128 * 1024;
    const u16*   Wdb = Wd + (size_t)batch * 256 * 1024;
    const u16*   Wub = Wu + (size_t)batch * 1024 * 256;
    const float* bdb = bd + batch * 256;
    const float* bub = bu + batch * 1024;
    float*       ob  = out + (size_t)batch * 2048 * 1024 + (size_t)mblk * 128 * 1024;

    constexpr int XO[3] = {0, 24576, 49152};
    constexpr int WO[3] = {8192, 32768, 57344};

    // ============== phase 1: R = relu(x @ Wd^T + bd), ring-3, depth-2 ======
    const int wm1 = wave >> 2, wn1 = wave & 3;   // 2x4 over 128x256

    // x staging: thread covers 16 elems of one row (2 swizzled store8)
    const int xrow = tid >> 2;                  // 0..127
    const int xcs  = (tid & 3) * 16;            // col start (elems)
    const int s0   = (tid & 3) * 2;
    const int xd0  = (xrow * 8 + (s0 ^ (xrow & 7))) * 8;
    const int xd1  = (xrow * 8 + ((s0 + 1) ^ (xrow & 7))) * 8;
    // Wd staging: 4 DMA/thread; permuted global col (XOR is involutive)
    const int wrow  = tid >> 3;                 // + r*64
    const int wgcol = ((tid & 7) ^ (wrow & 7)) * 8;

    // bias preload (retired early; keeps loop vmcnt counts exact)
    float bdv[4];
    #pragma unroll
    for (int ni = 0; ni < 4; ++ni) bdv[ni] = bdb[wn1 * 64 + ni * 16 + rl];
    MEMF();

    auto ldx = [&](int kt, float4* d) {
        const float* p = xb + (size_t)xrow * 1024 + kt + xcs;
        d[0] = *(const float4*)(p);
        d[1] = *(const float4*)(p + 4);
        d[2] = *(const float4*)(p + 8);
        d[3] = *(const float4*)(p + 12);
    };
    auto stx = [&](u16* xbuf, const float4* d) {
        store8(xbuf + xd0, d[0], d[1]);
        store8(xbuf + xd1, d[2], d[3]);
    };
    auto stage_wd = [&](int kt, u16* wbuf) {
        #pragma unroll
        for (int r = 0; r < 4; ++r)
            gload_lds16(Wdb + (size_t)(r * 64 + wrow) * 1024 + kt + wgcol,
                        wbuf + r * 4096 + wave * 512);
    };

    f32x4 acc1[4][4] = {};
    auto comp1 = [&](const u16* xbuf, const u16* wbuf) {
        #pragma unroll
        for (int kk = 0; kk < 2; ++kk) {
            bf16x8 av[4], bv[4];
            #pragma unroll
            for (int mi = 0; mi < 4; ++mi) {
                const int row = wm1 * 64 + mi * 16 + rl;
                av[mi] = *(const bf16x8*)(xbuf + (row * 8 + ((kk * 4 + quad) ^ rxl)) * 8);
            }
            #pragma unroll
            for (int ni = 0; ni < 4; ++ni) {
                const int row = wn1 * 64 + ni * 16 + rl;
                bv[ni] = *(const bf16x8*)(wbuf + (row * 8 + ((kk * 4 + quad) ^ rxl)) * 8);
            }
            #pragma unroll
            for (int mi = 0; mi < 4; ++mi)
                #pragma unroll
                for (int ni = 0; ni < 4; ++ni)
                    acc1[mi][ni] = __builtin_amdgcn_mfma_f32_16x16x32_bf16(
                        av[mi], bv[ni], acc1[mi][ni], 0, 0, 0);
        }
    };

    // prologue: stage iters 0,1 (in-flight after: bdv4 | x0,D0 | x1,D1)
    float4 xa[2][4];
    ldx(0, xa[0]);  stage_wd(0, lds + WO[0]);
    MEMF();
    ldx(64, xa[1]); stage_wd(64, lds + WO[1]);
    asm volatile("s_waitcnt vmcnt(12)" ::: "memory");   // x0 (and bdv) done
    stx(lds + XO[0], xa[0]);
    asm volatile("s_waitcnt vmcnt(8)" ::: "memory");    // D0 done
    asm volatile("s_waitcnt lgkmcnt(0)" ::: "memory");
    barx();

    #pragma unroll
    for (int t = 0; t < 16; ++t) {
        const int cb = t % 3, nb1 = (t + 1) % 3, nb2 = (t + 2) % 3;
        if (t < 14) {
            ldx((t + 2) * 64, xa[t & 1]);                // x(t+2)
            stage_wd((t + 2) * 64, lds + WO[nb2]);       // D(t+2)
        }
        comp1(lds + XO[cb], lds + WO[cb]);
        // retire x(t+1)+D(t+1); keep x(t+2)+D(t+2) in flight
        if (t < 14)       asm volatile("s_waitcnt vmcnt(8)" ::: "memory");
        else if (t == 14) asm volatile("s_waitcnt vmcnt(0)" ::: "memory");
        if (t < 15) {
            stx(lds + XO[nb1], xa[(t + 1) & 1]);
            asm volatile("s_waitcnt lgkmcnt(0)" ::: "memory");
        }
        barx();
    }

    // ============== phase 2: out = x + R @ Wu^T + bu =======================
    const int wm2 = wave >> 1, wn2 = wave & 1;   // 4x2 over 128 x 64-chunk
    const int srow = tid >> 5, ss = tid & 31;
    const int wugcol = ((ss & 24) | ((ss & 7) ^ (srow & 7))) * 8;
    u16* const wub0 = lds + 32768;
    u16* const wub1 = lds + 49152;

    auto stage_wu = [&](int c, u16* buf) {
        #pragma unroll
        for (int rr = 0; rr < 4; ++rr)
            gload_lds16(Wub + (size_t)(c * 64 + rr * 16 + srow) * 256 + wugcol,
                        buf + rr * 4096 + wave * 512);
    };
    // residual x + bias prefetch for one chunk: 18 loads -> regs
    auto ldxqb = [&](int c, float* dq) {
        #pragma unroll
        for (int ni = 0; ni < 2; ++ni) {
            const int colg = c * 64 + wn2 * 32 + ni * 16 + rl;
            #pragma unroll
            for (int mi = 0; mi < 2; ++mi)
                #pragma unroll
                for (int i = 0; i < 4; ++i)
                    dq[ni * 8 + mi * 4 + i] =
                        xb[(size_t)(wm2 * 32 + mi * 16 + quad * 4 + i) * 1024 + colg];
            dq[16 + ni] = bub[colg];
        }
    };

    // transition: issue chunk-0 DMA + chunk-0 regs under epilogue-1's VALU
    stage_wu(0, wub0);      // D0
    MEMF();
    float xqb[2][18];
    ldxqb(0, xqb[0]);       // q0 (18)

    // epilogue-1: bias + relu -> Rs at lds[0,32768) (ring bufs dead)
    #pragma unroll
    for (int ni = 0; ni < 4; ++ni) {
        const int col = wn1 * 64 + ni * 16 + rl;
        const int lbc = col >> 3, hi = lbc & 24, c7 = lbc & 7, cl = col & 7;
        #pragma unroll
        for (int mi = 0; mi < 4; ++mi)
            #pragma unroll
            for (int i = 0; i < 4; ++i) {
                const int row = wm1 * 64 + mi * 16 + quad * 4 + i;
                const int phys = hi | (c7 ^ (row & 7));
                lds[row * 256 + phys * 8 + cl] =
                    f2bf(fmaxf(acc1[mi][ni][i] + bdv[ni], 0.0f));
            }
    }
    asm volatile("s_waitcnt lgkmcnt(0)" ::: "memory");
    asm volatile("s_waitcnt vmcnt(18)" ::: "memory");   // D0 done, q0 may fly
    barx();

    // af hoist: R A-fragments to registers (64 VGPR); Rs then dead
    bf16x8 af[2][8];
    #pragma unroll
    for (int mi = 0; mi < 2; ++mi) {
        const int row = wm2 * 32 + mi * 16 + rl;
        #pragma unroll
        for (int t = 0; t < 8; ++t) {
            const int lb = t * 4 + quad;
            const int phys = (lb & 24) | ((lb & 7) ^ rxl);
            af[mi][t] = *(const bf16x8*)(lds + (row * 32 + phys) * 8);
        }
    }

    #pragma unroll
    for (int c = 0; c < 16; ++c) {
        const u16* wcur = (c & 1) ? wub1 : wub0;
        if (c < 15) {
            ldxqb(c + 1, xqb[(c + 1) & 1]);              // q(c+1): 18
            MEMF();
            stage_wu(c + 1, (c & 1) ? wub0 : wub1);      // D(c+1): 4
        }
        f32x4 acc2[2][2] = {};
        #pragma unroll
        for (int t = 0; t < 8; ++t) {
            bf16x8 bv[2];
            #pragma unroll
            for (int ni = 0; ni < 2; ++ni) {
                const int row = wn2 * 32 + ni * 16 + rl;
                const int lb = t * 4 + quad;
                const int phys = (lb & 24) | ((lb & 7) ^ rxl);
                bv[ni] = *(const bf16x8*)(wcur + (row * 32 + phys) * 8);
            }
            #pragma unroll
            for (int mi = 0; mi < 2; ++mi)
                #pragma unroll
                for (int ni = 0; ni < 2; ++ni)
                    acc2[mi][ni] = __builtin_amdgcn_mfma_f32_16x16x32_bf16(
                        af[mi][t], bv[ni], acc2[mi][ni], 0, 0, 0);
        }
        // retire prev chunk's stores (c>0) / q0 (c==0); keep q(c+1)+D(c+1)
        if (c < 15) asm volatile("s_waitcnt vmcnt(22)" ::: "memory");

        // epilogue-2: bias + fp32 residual -> fp32 out (16 stores)
        #pragma unroll
        for (int ni = 0; ni < 2; ++ni) {
            const int colg = c * 64 + wn2 * 32 + ni * 16 + rl;
            const float bval = xqb[c & 1][16 + ni];
            #pragma unroll
            for (int mi = 0; mi < 2; ++mi)
                #pragma unroll
                for (int i = 0; i < 4; ++i) {
                    const int rowl = wm2 * 32 + mi * 16 + quad * 4 + i;
                    ob[(size_t)rowl * 1024 + colg] =
                        acc2[mi][ni][i] + bval + xqb[c & 1][ni * 8 + mi * 4 + i];
                }
        }
        if (c < 15) {
            // retire q(c+1)+D(c+1) (D needed for next chunk); keep stores(c)
            asm volatile("s_waitcnt vmcnt(16)" ::: "memory");
            barx();
        }
    }
}

// ---------------------------------------------------------------------------
extern "C" void kernel_launch(void* const* d_in, const int* in_sizes, int n_in,
                              void* d_out, int out_size, void* d_ws, size_t ws_size,
                              hipStream_t stream) {
    const float* hidden = (const float*)d_in[0];   // (16, 2048, 1024) fp32
    const float* prob   = (const float*)d_in[1];   // (16, 8) fp32
    const float* w_down = (const float*)d_in[2];   // (8, 256, 1024) fp32
    const float* b_down = (const float*)d_in[3];   // (8, 256) fp32
    const float* w_up   = (const float*)d_in[4];   // (8, 1024, 256) fp32
    const float* b_up   = (const float*)d_in[5];   // (8, 1024) fp32
    float* out = (float*)d_out;                    // (16, 2048, 1024) fp32

    // workspace: merged weights (bf16) + biases (fp32), ~16.1 MB
    u16* Wd = (u16*)d_ws;                               // 16*256*1024 bf16
    u16* Wu = Wd + (size_t)16 * 256 * 1024;             // 16*1024*256 bf16
    float* bd = (float*)(Wu + (size_t)16 * 1024 * 256); // 16*256 f32
    float* bu = bd + 16 * 256;                          // 16*1024 f32

    merge_kernel<<<336, 256, 0, stream>>>(prob, w_down, b_down, w_up, b_up,
                                          Wd, Wu, bd, bu);

    fused_adapter<<<256, 512, 0, stream>>>(hidden, Wd, Wu, bd, bu, out);
}